// Round 4
// baseline (110.485 us; speedup 1.0000x reference)
//
#include <hip/hip_runtime.h>
#include <cstdint>

#define CKDIM 128
#define MDIM  4096
#define QDIM  4096
#define BATCH 4

typedef __attribute__((ext_vector_type(8))) _Float16 half8;
typedef __attribute__((ext_vector_type(4))) float    f32x4;

#if __has_builtin(__builtin_amdgcn_exp2f)
#define EXP2(x) __builtin_amdgcn_exp2f(x)
#else
#define EXP2(x) exp2f(x)
#endif

__device__ inline void gl_lds16(const void* g, const void* l) {
    __builtin_amdgcn_global_load_lds(
        (const __attribute__((address_space(1))) unsigned*)g,
        (__attribute__((address_space(3))) unsigned*)l, 16, 0, 0);
}

// ---- 1) fused: transpose-convert X[b][k][n] fp32 -> Xt[b][n][k] fp16,
//      asq[b][m] = sum_k Mk^2 (fp32-exact), sums[] zeroing by Qk half.
__global__ void convert_kernel(const float* __restrict__ Mk, const float* __restrict__ Qk,
                               _Float16* __restrict__ At, _Float16* __restrict__ Bt,
                               float* __restrict__ asq, float* __restrict__ sums) {
    __shared__ _Float16 T[128 * 130];
    __shared__ float    asqp[16][128];
    const int blk = blockIdx.x;                  // 256: mat(2) x b(4) x tile(32)
    const int mat = blk >> 7;
    const int b   = (blk >> 5) & 3;
    const int t   = blk & 31;
    const float*  src = (mat ? Qk : Mk) + (size_t)b * CKDIM * MDIM + t * 128;
    _Float16*     dst = (mat ? Bt : At) + ((size_t)b * MDIM + (size_t)t * 128) * CKDIM;
    const int tid = threadIdx.x;
    const int kg  = tid >> 4;
    const int ng  = tid & 15;

    float sq[8] = {0.f, 0.f, 0.f, 0.f, 0.f, 0.f, 0.f, 0.f};
    #pragma unroll
    for (int it = 0; it < 8; ++it) {
        int k = it * 16 + kg;
        const float* g = src + (size_t)k * MDIM + ng * 8;
        float4 v0 = *(const float4*)g;
        float4 v1 = *(const float4*)(g + 4);
        _Float16* p = &T[k * 130 + ng * 8];
        p[0] = (_Float16)v0.x; p[1] = (_Float16)v0.y; p[2] = (_Float16)v0.z; p[3] = (_Float16)v0.w;
        p[4] = (_Float16)v1.x; p[5] = (_Float16)v1.y; p[6] = (_Float16)v1.z; p[7] = (_Float16)v1.w;
        if (mat == 0) {
            sq[0] += v0.x * v0.x; sq[1] += v0.y * v0.y;
            sq[2] += v0.z * v0.z; sq[3] += v0.w * v0.w;
            sq[4] += v1.x * v1.x; sq[5] += v1.y * v1.y;
            sq[6] += v1.z * v1.z; sq[7] += v1.w * v1.w;
        }
    }
    if (mat == 0) {
        #pragma unroll
        for (int j = 0; j < 8; ++j) asqp[kg][ng * 8 + j] = sq[j];
    } else {
        if (tid < 128) sums[(blk & 127) * 128 + tid] = 0.f;
    }
    __syncthreads();
    #pragma unroll
    for (int it = 0; it < 8; ++it) {
        int pid = it * 256 + tid;
        int n = pid >> 4, c = pid & 15;
        half8 o;
        #pragma unroll
        for (int j = 0; j < 8; ++j) o[j] = T[(c * 8 + j) * 130 + n];
        *(half8*)(dst + (size_t)n * CKDIM + c * 8) = o;
    }
    if (mat == 0 && tid < 128) {
        float s = 0.f;
        #pragma unroll
        for (int g = 0; g < 16; ++g) s += asqp[g][tid];
        asq[b * MDIM + t * 128 + tid] = s;
    }
}

// ---- 2/3) GEMM passes. 128x128 tile, 2x2 waves, K staged in 2 halves of 64
//      (32 KB LDS -> 4 blocks/CU). XCD-chunked block swizzle.
// WRITE=0: exp + column-sum atomics. WRITE=1: write exp/sum.
template <int WRITE>
__global__ __launch_bounds__(256, 4) void gemm_pass(
        const _Float16* __restrict__ At, const _Float16* __restrict__ Bt,
        const float* __restrict__ asq, float* __restrict__ sums,
        float* __restrict__ out) {
    __shared__ char smem[32768];                 // A half (16KB) | B half (16KB)
    const int tid  = threadIdx.x;
    const int lane = tid & 63;
    const int wv   = tid >> 6;
    const int wr   = wv >> 1;
    const int wc   = wv & 1;
    // XCD-chunked swizzle: XCD x gets contiguous tile region [x*512, x*512+512)
    const int wg   = blockIdx.x;
    const int swz  = ((wg & 7) << 9) | (wg >> 3);
    const int b    = swz >> 10;
    const int rr   = swz & 1023;
    const int bm0  = (rr >> 5) << 7;
    const int bq0  = (rr & 31) << 7;

    const char* Abase = (const char*)(At + ((size_t)b * MDIM + bm0) * CKDIM);
    const char* Bbase = (const char*)(Bt + ((size_t)b * QDIM + bq0) * CKDIM);
    char* lA = (char*)smem;
    char* lB = (char*)smem + 16384;

    const int g4 = lane >> 4;
    const int i  = lane & 15;
    f32x4 acc[4][4];
    #pragma unroll
    for (int mf = 0; mf < 4; ++mf)
        #pragma unroll
        for (int nf = 0; nf < 4; ++nf) acc[mf][nf] = (f32x4){0.f, 0.f, 0.f, 0.f};

    #pragma unroll
    for (int ks = 0; ks < 2; ++ks) {
        if (ks) __syncthreads();                 // drain prev half's reads
        // stage 16 KB per matrix: linear LDS dest, inverse-swizzled source
        #pragma unroll
        for (int r4 = 0; r4 < 4; ++r4) {
            int c4 = r4 * 4 + wv;                // 1 KB chunk id (wave-uniform)
            unsigned Dw = (unsigned)c4 << 10;
            int n = (c4 << 3) + (lane >> 3);     // LDS row this lane fills
            int c = (lane & 7) << 4;             // byte col within 128B row
            unsigned S = (unsigned)(n * 256 + ks * 128 + (c ^ ((n & 7) << 4)));
            gl_lds16(Abase + S, lA + Dw);
            gl_lds16(Bbase + S, lB + Dw);
        }
        asm volatile("s_waitcnt vmcnt(0)" ::: "memory");
        __syncthreads();
        #pragma unroll
        for (int t = 0; t < 2; ++t) {            // 2 k-steps of 32 per half
            const int kb = t * 64 + g4 * 16;
            half8 af[4], bfr[4];
            #pragma unroll
            for (int mf = 0; mf < 4; ++mf) {
                int n = wr * 64 + mf * 16 + i;
                af[mf] = *(const half8*)(lA + n * 128 + (kb ^ ((n & 7) << 4)));
            }
            #pragma unroll
            for (int nf = 0; nf < 4; ++nf) {
                int n = wc * 64 + nf * 16 + i;
                bfr[nf] = *(const half8*)(lB + n * 128 + (kb ^ ((n & 7) << 4)));
            }
            __builtin_amdgcn_s_setprio(1);
            #pragma unroll
            for (int mf = 0; mf < 4; ++mf)
                #pragma unroll
                for (int nf = 0; nf < 4; ++nf)
                    acc[mf][nf] = __builtin_amdgcn_mfma_f32_16x16x32_f16(af[mf], bfr[nf], acc[mf][nf], 0, 0, 0);
            __builtin_amdgcn_s_setprio(0);
        }
    }

    const float ALPHA = 1.44269504088896340736f / 11.31370849898476039041f; // log2(e)/sqrt(128)
    if (WRITE) {
        float rs[4];
        #pragma unroll
        for (int nf = 0; nf < 4; ++nf)
            rs[nf] = 1.0f / sums[(b << 12) + bq0 + wc * 64 + nf * 16 + i];
        #pragma unroll
        for (int mf = 0; mf < 4; ++mf) {
            int   mbase = bm0 + wr * 64 + mf * 16 + g4 * 4;
            f32x4 aq    = *(const f32x4*)&asq[b * MDIM + mbase];
            #pragma unroll
            for (int nf = 0; nf < 4; ++nf) {
                size_t outbase = ((size_t)b * MDIM + mbase) * QDIM + (bq0 + wc * 64 + nf * 16 + i);
                #pragma unroll
                for (int r = 0; r < 4; ++r) {
                    float e = EXP2((2.0f * acc[mf][nf][r] - aq[r]) * ALPHA);
                    __builtin_nontemporal_store(e * rs[nf], &out[outbase + (size_t)r * QDIM]);
                }
            }
        }
    } else {
        float colsum[4] = {0.f, 0.f, 0.f, 0.f};
        #pragma unroll
        for (int mf = 0; mf < 4; ++mf) {
            int   mbase = bm0 + wr * 64 + mf * 16 + g4 * 4;
            f32x4 aq    = *(const f32x4*)&asq[b * MDIM + mbase];
            #pragma unroll
            for (int nf = 0; nf < 4; ++nf)
                #pragma unroll
                for (int r = 0; r < 4; ++r)
                    colsum[nf] += EXP2((2.0f * acc[mf][nf][r] - aq[r]) * ALPHA);
        }
        #pragma unroll
        for (int nf = 0; nf < 4; ++nf) {
            float s = colsum[nf];
            s += __shfl_xor(s, 16);
            s += __shfl_xor(s, 32);
            if (lane < 16) {
                __hip_atomic_fetch_add(&sums[(b << 12) + bq0 + wc * 64 + nf * 16 + lane], s,
                                       __ATOMIC_RELAXED, __HIP_MEMORY_SCOPE_AGENT);
            }
        }
    }
}

extern "C" void kernel_launch(void* const* d_in, const int* in_sizes, int n_in,
                              void* d_out, int out_size, void* d_ws, size_t ws_size,
                              hipStream_t stream) {
    const float* Mk = (const float*)d_in[0];
    const float* Qk = (const float*)d_in[1];
    float* out = (float*)d_out;

    _Float16* At   = (_Float16*)d_ws;                               // 4 MB
    _Float16* Bt   = At + (size_t)BATCH * MDIM * CKDIM;             // 4 MB
    float*    sums = (float*)(Bt + (size_t)BATCH * MDIM * CKDIM);   // 64 KB
    float*    asq  = sums + BATCH * QDIM;                           // 64 KB

    convert_kernel<<<256, 256, 0, stream>>>(Mk, Qk, At, Bt, asq, sums);
    gemm_pass<0><<<4096, 256, 0, stream>>>(At, Bt, asq, sums, out);
    gemm_pass<1><<<4096, 256, 0, stream>>>(At, Bt, asq, sums, out);
}